// Round 1
// baseline (29989.853 us; speedup 1.0000x reference)
//
#include <hip/hip_runtime.h>
#include <stdint.h>

#define DIM   1024
#define TLEN  1024
#define BATCH 32
#define NCODE 256

// ws layout in floats
#define WS_CC   16
#define WS_IDX  272
#define WS_CGI  33040
#define WS_H    819472
#define WS_HP   34373904

#define OUT_IDX 33554432
#define OUT_TOT 33587200

// ---------------- codebook norms ----------------
__global__ __launch_bounds__(256) void k_norms(const float* __restrict__ cb,
                                               float* __restrict__ cc) {
  int c = blockIdx.x;
  int t = threadIdx.x;
  const float4* p = (const float4*)(cb + (size_t)c * DIM);
  float4 v = p[t];
  float s = v.x*v.x + v.y*v.y + v.z*v.z + v.w*v.w;
#pragma unroll
  for (int m = 1; m < 64; m <<= 1) s += __shfl_xor(s, m);
  __shared__ float ls[4];
  if ((t & 63) == 0) ls[t >> 6] = s;
  __syncthreads();
  if (t == 0) cc[c] = ls[0] + ls[1] + ls[2] + ls[3];
}

// ---------------- quantize: scores + argmin + outputs + sse ----------------
__global__ __launch_bounds__(256) void k_quant(
    const float* __restrict__ F, const float* __restrict__ CB,
    const float* __restrict__ cc, float* __restrict__ qout,
    float* __restrict__ idxf, int* __restrict__ idxi,
    float* __restrict__ sse_acc)
{
  __shared__ float Fl[32][33];
  __shared__ float Cl[256][33];
  __shared__ float ccl[256];
  __shared__ float sumff[32];
  __shared__ unsigned long long rowmin[32];
  __shared__ float wsum[4];

  const int tid = threadIdx.x;
  const size_t m0 = (size_t)blockIdx.x * 32;

  const int tm = tid >> 5;   // 0..7   rows r = tm + 8i
  const int tn = tid & 31;   // 0..31  codes c = tn + 32j
  const int ar = tid >> 3;   // 0..31  staging row
  const int ac = tid & 7;    // 0..7   staging float4 idx

  if (tid < 32) rowmin[tid] = ~0ull;
  ccl[tid] = cc[tid];

  float acc[4][8];
#pragma unroll
  for (int i = 0; i < 4; ++i)
#pragma unroll
    for (int j = 0; j < 8; ++j) acc[i][j] = 0.f;
  float ffp = 0.f;

  for (int k0 = 0; k0 < DIM; k0 += 32) {
    __syncthreads();
    {
      float4 v = *(const float4*)&F[(m0 + ar) * DIM + k0 + 4 * ac];
      Fl[ar][4*ac+0] = v.x; Fl[ar][4*ac+1] = v.y;
      Fl[ar][4*ac+2] = v.z; Fl[ar][4*ac+3] = v.w;
      ffp += v.x*v.x + v.y*v.y + v.z*v.z + v.w*v.w;
    }
#pragma unroll
    for (int rep = 0; rep < 8; ++rep) {
      int r = ar + 32 * rep;
      float4 v = *(const float4*)&CB[(size_t)r * DIM + k0 + 4 * ac];
      Cl[r][4*ac+0] = v.x; Cl[r][4*ac+1] = v.y;
      Cl[r][4*ac+2] = v.z; Cl[r][4*ac+3] = v.w;
    }
    __syncthreads();
    for (int kk = 0; kk < 32; ++kk) {
      float a[4], b[8];
#pragma unroll
      for (int i = 0; i < 4; ++i) a[i] = Fl[tm + 8*i][kk];
#pragma unroll
      for (int j = 0; j < 8; ++j) b[j] = Cl[tn + 32*j][kk];
#pragma unroll
      for (int i = 0; i < 4; ++i)
#pragma unroll
        for (int j = 0; j < 8; ++j) acc[i][j] += a[i] * b[j];
    }
  }
  {
    float s = ffp;
    s += __shfl_xor(s, 1); s += __shfl_xor(s, 2); s += __shfl_xor(s, 4);
    if (ac == 0) sumff[ar] = s;
  }
  __syncthreads();
#pragma unroll
  for (int i = 0; i < 4; ++i) {
    float sf = sumff[tm + 8*i];
    unsigned long long best = ~0ull;
#pragma unroll
    for (int j = 0; j < 8; ++j) {
      int c = tn + 32*j;
      float sc = (sf - 2.f * acc[i][j]) + ccl[c];   // mimic ref rounding order
      unsigned ub = __float_as_uint(sc);
      ub = (ub & 0x80000000u) ? ~ub : (ub | 0x80000000u);
      unsigned long long key = ((unsigned long long)ub << 32) | (unsigned)c;
      if (key < best) best = key;
    }
    atomicMin(&rowmin[tm + 8*i], best);
  }
  __syncthreads();
  if (tid < 32) {
    int code = (int)(rowmin[tid] & 0xffffffffull);
    idxi[m0 + tid] = code;
    idxf[m0 + tid] = (float)code;
  }
  float ssep = 0.f;
  for (int r = 0; r < 32; ++r) {
    int code = (int)(rowmin[r] & 0xffffffffull);
    float4 q = *(const float4*)&CB[(size_t)code * DIM + 4 * tid];
    float4 f = *(const float4*)&F[(m0 + r) * DIM + 4 * tid];
    *(float4*)&qout[(m0 + r) * DIM + 4 * tid] = q;
    float dx = f.x-q.x, dy = f.y-q.y, dz = f.z-q.z, dw = f.w-q.w;
    ssep += dx*dx + dy*dy + dz*dz + dw*dw;
  }
  {
    float s = ssep;
#pragma unroll
    for (int m = 1; m < 64; m <<= 1) s += __shfl_xor(s, m);
    if ((tid & 63) == 0) wsum[tid >> 6] = s;
  }
  __syncthreads();
  if (tid == 0) atomicAdd(sse_acc, wsum[0] + wsum[1] + wsum[2] + wsum[3]);
}

// ---------------- generic NT GEMM: C[M,N] = A[M,K] * B[N,K]^T + bias ----------------
template<int BM, int BN, int BK>
__global__ __launch_bounds__(256) void k_gemm_nt(
    const float* __restrict__ A, const float* __restrict__ B,
    const float* __restrict__ bias, float* __restrict__ C,
    int M, int N, int K)
{
  __shared__ float Al[BM][BK + 1];
  __shared__ float Bl[BN][BK + 1];
  const int tid = threadIdx.x;
  const int tm = tid >> 4;   // 0..15
  const int tn = tid & 15;   // 0..15
  const size_t m0 = (size_t)blockIdx.y * BM;
  const size_t n0 = (size_t)blockIdx.x * BN;
  float acc[BM/16][BN/16];
#pragma unroll
  for (int i = 0; i < BM/16; ++i)
#pragma unroll
    for (int j = 0; j < BN/16; ++j) acc[i][j] = 0.f;

  constexpr int F4R = BK / 4;
  for (int k0 = 0; k0 < K; k0 += BK) {
    __syncthreads();
    for (int rr = tid; rr < BM * F4R; rr += 256) {
      int r = rr / F4R, c4 = rr % F4R;
      float4 v = *(const float4*)&A[(m0 + r) * K + k0 + 4 * c4];
      Al[r][4*c4+0] = v.x; Al[r][4*c4+1] = v.y;
      Al[r][4*c4+2] = v.z; Al[r][4*c4+3] = v.w;
    }
    for (int rr = tid; rr < BN * F4R; rr += 256) {
      int r = rr / F4R, c4 = rr % F4R;
      float4 v = *(const float4*)&B[(n0 + r) * K + k0 + 4 * c4];
      Bl[r][4*c4+0] = v.x; Bl[r][4*c4+1] = v.y;
      Bl[r][4*c4+2] = v.z; Bl[r][4*c4+3] = v.w;
    }
    __syncthreads();
    for (int kk = 0; kk < BK; ++kk) {
      float a[BM/16], b[BN/16];
#pragma unroll
      for (int i = 0; i < BM/16; ++i) a[i] = Al[tm + 16*i][kk];
#pragma unroll
      for (int j = 0; j < BN/16; ++j) b[j] = Bl[tn + 16*j][kk];
#pragma unroll
      for (int i = 0; i < BM/16; ++i)
#pragma unroll
        for (int j = 0; j < BN/16; ++j) acc[i][j] += a[i] * b[j];
    }
  }
#pragma unroll
  for (int i = 0; i < BM/16; ++i)
#pragma unroll
    for (int j = 0; j < BN/16; ++j) {
      size_t cn = n0 + tn + 16*j;
      C[(m0 + tm + 16*i) * N + cn] = acc[i][j] + bias[cn];
    }
}

// ---------------- persistent GRU ----------------
__global__ __launch_bounds__(1024, 4) void k_gru(
    const float* __restrict__ Whh, const float* __restrict__ bhh,
    const float* __restrict__ CGI, const int* __restrict__ idx,
    float* __restrict__ H, unsigned* __restrict__ counter)
{
  __shared__ float Wlds[12 * 1024];
  __shared__ float ghl[12 * 32];
  __shared__ int   idxl[32];
  __shared__ float bhl[12];

  const int w = blockIdx.x;              // owns dims d = 4w..4w+3
  const int tid = threadIdx.x;
  const int v = tid >> 6, l = tid & 63;
  const int bq = l >> 3, kq = l & 7;
  const int k0 = (v << 6) + (kq << 3);   // lane K-chunk base (8 floats)

  for (int j = 0; j < 12; ++j) {
    int g = j >> 2, dp = j & 3;
    int row = g * 1024 + 4 * w + dp;
    Wlds[j * 1024 + tid] = Whh[(size_t)row * 1024 + tid];
  }
  if (tid < 12) { int g = tid >> 2, dp = tid & 3; bhl[tid] = bhh[g * 1024 + 4 * w + dp]; }
  __syncthreads();

  for (int t = 0; t < TLEN; ++t) {
    if (tid < 32) idxl[tid] = idx[tid * TLEN + t];
    if (tid < 384) ghl[tid] = bhl[tid >> 5];
    __syncthreads();

    if (t > 0) {
      float hreg[4][8];
#pragma unroll
      for (int i = 0; i < 4; ++i) {
        int b = 4 * bq + i;
        const float* hp = H + (size_t)(b * TLEN + (t - 1)) * DIM + k0;
        float4 x0 = *(const float4*)hp;
        float4 x1 = *(const float4*)(hp + 4);
        hreg[i][0]=x0.x; hreg[i][1]=x0.y; hreg[i][2]=x0.z; hreg[i][3]=x0.w;
        hreg[i][4]=x1.x; hreg[i][5]=x1.y; hreg[i][6]=x1.z; hreg[i][7]=x1.w;
      }
      float acc[12][4];
#pragma unroll
      for (int j = 0; j < 12; ++j) {
        const float* wp = Wlds + j * 1024 + k0;
        float4 w0 = *(const float4*)wp;
        float4 w1 = *(const float4*)(wp + 4);
        float wv[8] = {w0.x,w0.y,w0.z,w0.w,w1.x,w1.y,w1.z,w1.w};
#pragma unroll
        for (int i = 0; i < 4; ++i) {
          float s = 0.f;
#pragma unroll
          for (int kk = 0; kk < 8; ++kk) s += hreg[i][kk] * wv[kk];
          acc[j][i] = s;
        }
      }
#pragma unroll
      for (int j = 0; j < 12; ++j)
#pragma unroll
        for (int i = 0; i < 4; ++i) {
          float s = acc[j][i];
          s += __shfl_xor(s, 1);
          s += __shfl_xor(s, 2);
          s += __shfl_xor(s, 4);
          acc[j][i] = s;
        }
      if (kq == 0) {
#pragma unroll
        for (int j = 0; j < 12; ++j)
#pragma unroll
          for (int i = 0; i < 4; ++i)
            atomicAdd(&ghl[j * 32 + 4 * bq + i], acc[j][i]);
      }
    }
    __syncthreads();

    if (tid < 128) {
      int dp = tid >> 5, b = tid & 31;
      int code = idxl[b];
      int dg = 4 * w + dp;
      const float* cgi = CGI + (size_t)code * 3072;
      float ir = cgi[dg], iz = cgi[1024 + dg], inn = cgi[2048 + dg];
      float gr = ghl[dp * 32 + b];
      float gz = ghl[(4 + dp) * 32 + b];
      float gn = ghl[(8 + dp) * 32 + b];
      float h_old = (t > 0) ? H[(size_t)(b * TLEN + (t - 1)) * DIM + dg] : 0.f;
      float r = 1.f / (1.f + expf(-(ir + gr)));
      float z = 1.f / (1.f + expf(-(iz + gz)));
      float n = tanhf(inn + r * gn);
      float hn = (1.f - z) * n + z * h_old;
      __hip_atomic_store(&H[(size_t)(b * TLEN + t) * DIM + dg], hn,
                         __ATOMIC_RELAXED, __HIP_MEMORY_SCOPE_AGENT);
    }
    __syncthreads();
    if (tid == 0) {
      __hip_atomic_fetch_add(counter, 1u, __ATOMIC_ACQ_REL, __HIP_MEMORY_SCOPE_AGENT);
      unsigned target = 256u * (unsigned)(t + 1);
      long poll = 0;
      while (__hip_atomic_load(counter, __ATOMIC_ACQUIRE, __HIP_MEMORY_SCOPE_AGENT) < target) {
        __builtin_amdgcn_s_sleep(8);
        if (++poll > 2000000L) break;   // fail-safe against deadlock (wrong > hung)
      }
    }
    __syncthreads();
  }
}

// ---------------- CPC loss dots ----------------
__global__ __launch_bounds__(256) void k_loss(
    const float* __restrict__ Hp, const float* __restrict__ F,
    const int* __restrict__ nidx, float* __restrict__ cp_acc)
{
  int blk = blockIdx.x;
  int k, t;
  if (blk < 1023)      { k = 1; t = blk; }
  else if (blk < 2045) { k = 2; t = blk - 1023; }
  else                 { k = 3; t = blk - 2045; }
  const int tid = threadIdx.x;
  const int wv = tid >> 6, l = tid & 63;
  __shared__ float ssum[4];
  float lsum = 0.f;
  for (int bi = 0; bi < 8; ++bi) {
    int b = wv * 8 + bi;
    const float4* hp = (const float4*)(Hp + (size_t)(b * TLEN + t) * DIM);
    const float4* fp = (const float4*)(F + (size_t)(b * TLEN + t + k) * DIM);
    int nb = nidx[(k - 1) * TLEN * BATCH + t * BATCH + b];
    const float4* fn = (const float4*)(F + (size_t)(nb * TLEN + t) * DIM);
    float pos = 0.f, neg = 0.f;
#pragma unroll
    for (int c = 0; c < 4; ++c) {
      float4 h4 = hp[l + 64 * c];
      float4 p4 = fp[l + 64 * c];
      float4 n4 = fn[l + 64 * c];
      pos += h4.x*p4.x + h4.y*p4.y + h4.z*p4.z + h4.w*p4.w;
      neg += h4.x*n4.x + h4.y*n4.y + h4.z*n4.z + h4.w*n4.w;
    }
#pragma unroll
    for (int m = 1; m < 64; m <<= 1) {
      pos += __shfl_xor(pos, m);
      neg += __shfl_xor(neg, m);
    }
    if (l == 0) lsum += 1.f / (1.f + expf(neg - pos));
  }
  if (l == 0) ssum[wv] = lsum;
  __syncthreads();
  if (tid == 0) {
    float mean = (ssum[0] + ssum[1] + ssum[2] + ssum[3]) * (1.f / 32.f);
    atomicAdd(cp_acc, -logf(mean));
  }
}

__global__ void k_final(const float* __restrict__ sse, const float* __restrict__ cp,
                        float* __restrict__ out) {
  out[0] = cp[0] * (1.f / 3063.f) + 1.25f * sse[0] * (1.f / 33554432.f);
}

extern "C" void kernel_launch(void* const* d_in, const int* in_sizes, int n_in,
                              void* d_out, int out_size, void* d_ws, size_t ws_size,
                              hipStream_t stream)
{
  const float* F    = (const float*)d_in[0];
  const float* CB   = (const float*)d_in[1];
  const float* Wih  = (const float*)d_in[2];
  const float* Whh  = (const float*)d_in[3];
  const float* bih  = (const float*)d_in[4];
  const float* bhh  = (const float*)d_in[5];
  const float* Wp   = (const float*)d_in[6];
  const float* bp   = (const float*)d_in[7];
  const int*   nidx = (const int*)d_in[8];
  float* out = (float*)d_out;
  float* ws  = (float*)d_ws;

  hipMemsetAsync(d_ws, 0, 64, stream);   // counter, sse, cp accumulators

  k_norms<<<NCODE, 256, 0, stream>>>(CB, ws + WS_CC);
  k_quant<<<1024, 256, 0, stream>>>(F, CB, ws + WS_CC, out,
                                    out + OUT_IDX, (int*)(ws + WS_IDX), ws + 1);
  k_gemm_nt<64,128,16><<<dim3(3072/128, 256/64), 256, 0, stream>>>(
      CB, Wih, bih, ws + WS_CGI, 256, 3072, 1024);
  k_gru<<<256, 1024, 0, stream>>>(Whh, bhh, ws + WS_CGI,
                                  (const int*)(ws + WS_IDX), ws + WS_H,
                                  (unsigned*)ws);
  k_gemm_nt<64,128,16><<<dim3(1024/128, 32768/64), 256, 0, stream>>>(
      ws + WS_H, Wp, bp, ws + WS_HP, 32768, 1024, 1024);
  k_loss<<<3066, 256, 0, stream>>>(ws + WS_HP, F, nidx, ws + 2);
  k_final<<<1, 1, 0, stream>>>(ws + 1, ws + 2, out + OUT_TOT);
}